// Round 4
// baseline (365.913 us; speedup 1.0000x reference)
//
#include <hip/hip_runtime.h>

#define N_NODES 8000
#define FEAT 64
#define HID 128
#define LOOKBACK 12
#define CAP 64
#define CHUNKS 16
#define ISZ 500          // rows per i-chunk (CHUNKS*ISZ == N_NODES)
#define PCAP 12          // per-(j,chunk) sublist capacity (Poisson(1) tail ~1e-13)

// ---------------- deterministic adjacency column-scan ----------------
// block b: jb = b & 31 (256 targets), ic = b >> 5 (i-chunk). Lane j reads
// adj[i][j] coalesced (256B/wave); appends source i in ascending order.
__global__ __launch_bounds__(256)
void scan_adj_kernel(const float* __restrict__ adj, int* __restrict__ pcnt,
                     int* __restrict__ plist) {
    const int jb = blockIdx.x & 31;
    const int ic = blockIdx.x >> 5;
    const int j = jb * 256 + threadIdx.x;
    if (j >= N_NODES) return;
    const int i0 = ic * ISZ;
    int c = 0;
    int* lp = plist + (long)j * (CHUNKS * PCAP) + ic * PCAP;
    #pragma unroll 1
    for (int i = i0; i < i0 + ISZ; i += 4) {
        float w0 = adj[(long)(i + 0) * N_NODES + j];
        float w1 = adj[(long)(i + 1) * N_NODES + j];
        float w2 = adj[(long)(i + 2) * N_NODES + j];
        float w3 = adj[(long)(i + 3) * N_NODES + j];
        if (w0 != 0.0f) { if (c < PCAP) lp[c] = i + 0; ++c; }
        if (w1 != 0.0f) { if (c < PCAP) lp[c] = i + 1; ++c; }
        if (w2 != 0.0f) { if (c < PCAP) lp[c] = i + 2; ++c; }
        if (w3 != 0.0f) { if (c < PCAP) lp[c] = i + 3; ++c; }
    }
    pcnt[ic * N_NODES + j] = c;
}

// ---------------- concat sublists (ascending chunk => ascending i) + weights ----------------
__global__ __launch_bounds__(256)
void concat_kernel(const int* __restrict__ pcnt, const int* __restrict__ plist,
                   int* __restrict__ cnt, int* __restrict__ lists,
                   float* __restrict__ degf,
                   const float* __restrict__ Wl1, const float* __restrict__ Wr1,
                   const float* __restrict__ Wl2, const float* __restrict__ Wr2,
                   float* __restrict__ Ws1, float* __restrict__ Wc2) {
    int g = blockIdx.x * 256 + threadIdx.x;
    if (g < N_NODES) {
        int tot = 0, kept = 0;
        int* dst = lists + (long)g * CAP;
        const int* src = plist + (long)g * (CHUNKS * PCAP);
        #pragma unroll 1
        for (int c = 0; c < CHUNKS; ++c) {
            int m = pcnt[c * N_NODES + g];
            tot += m;
            if (m > PCAP) m = PCAP;
            for (int e = 0; e < m; ++e) {
                if (kept < CAP) dst[kept++] = src[c * PCAP + e];
            }
        }
        cnt[g] = kept;
        degf[g] = (float)(tot > 0 ? tot : 1);
    } else if (g >= 8192) {
        int u = g - 8192;
        if (u < 128 * 128) {            // Ws1[k][j] = [Wl1;Wr1] row-stacked
            int k = u >> 7, j = u & 127;
            Ws1[u] = (k < 64) ? Wl1[k * 128 + j] : Wr1[(k - 64) * 128 + j];
        } else if (u < 2 * 128 * 128) { // Wc2[k][j] = [Wl2 | Wr2] col-stacked
            int w = u - 128 * 128;
            int k = w >> 7, j = w & 127;
            Wc2[w] = (j < 64) ? Wl2[k * 64 + j] : Wr2[k * 64 + (j - 64)];
        }
    }
}

// ---------------- init encoder: x[L,N,F] -> x0[N,F], 4 elems/thread ----------------
__global__ __launch_bounds__(256)
void init_enc_kernel(const float* __restrict__ x, const float* __restrict__ We1,
                     const float* __restrict__ be1, const float* __restrict__ We2,
                     const float* __restrict__ be2, float* __restrict__ out0) {
    __shared__ float sW1T[HID * LOOKBACK];   // [h][l]
    __shared__ float sB1[HID];
    __shared__ float sW2[HID];
    for (int e = threadIdx.x; e < HID * LOOKBACK; e += 256) {
        int l = e / HID, h = e % HID;
        sW1T[h * LOOKBACK + l] = We1[e];
    }
    for (int e = threadIdx.x; e < HID; e += 256) { sB1[e] = be1[e]; sW2[e] = We2[e]; }
    __syncthreads();
    int g = (blockIdx.x * 256 + threadIdx.x) * 4;
    if (g >= N_NODES * FEAT) return;
    float xv[4][LOOKBACK];
    #pragma unroll
    for (int l = 0; l < LOOKBACK; ++l) {
        float4 v = *reinterpret_cast<const float4*>(x + (long)l * N_NODES * FEAT + g);
        xv[0][l] = v.x; xv[1][l] = v.y; xv[2][l] = v.z; xv[3][l] = v.w;
    }
    float b2 = be2[0];
    float acc[4] = {b2, b2, b2, b2};
    for (int h = 0; h < HID; ++h) {
        float s0 = sB1[h], s1 = s0, s2 = s0, s3 = s0;
        #pragma unroll
        for (int l = 0; l < LOOKBACK; ++l) {
            float w = sW1T[h * LOOKBACK + l];
            s0 += xv[0][l] * w; s1 += xv[1][l] * w;
            s2 += xv[2][l] * w; s3 += xv[3][l] * w;
        }
        float w2 = sW2[h];
        acc[0] += fmaxf(s0, 0.0f) * w2; acc[1] += fmaxf(s1, 0.0f) * w2;
        acc[2] += fmaxf(s2, 0.0f) * w2; acc[3] += fmaxf(s3, 0.0f) * w2;
    }
    float4 o = {acc[0], acc[1], acc[2], acc[3]};
    *reinterpret_cast<float4*>(out0 + g) = o;
}

// ---------------- fused SAGE1 + proj + selfMLP ----------------
__global__ __launch_bounds__(256)
void sageproj_kernel(const float* __restrict__ h, const int* __restrict__ lists,
                     const int* __restrict__ cnt, const float* __restrict__ degf,
                     const float* __restrict__ Ws1, const float* __restrict__ bl1,
                     const float* __restrict__ Wc2, const float* __restrict__ bl2,
                     const float* __restrict__ Wf1, const float* __restrict__ bf1,
                     const float* __restrict__ Wf2, const float* __restrict__ bf2,
                     float* __restrict__ pl, float* __restrict__ q) {
    __shared__ float v[32][132];     // [node][k]: k<64 aggr, k>=64 h row
    __shared__ float rr[32][132];    // r1
    __shared__ float tt[32][132];    // t = relu(h@Wf1+bf1)
    __shared__ float xsL[32][68];    // xs
    const int tid = threadIdx.x;
    const int nb = blockIdx.x * 32;
    {   // gather: 8 threads/node, 8 feats each
        const int ln = tid >> 3, sub = tid & 7;
        const int n = nb + ln;
        const int f0 = sub * 8;
        const int m = cnt[n];
        const int* l = lists + (long)n * CAP;
        const float inv = 1.0f / degf[n];
        float acc[8] = {0, 0, 0, 0, 0, 0, 0, 0};
        for (int e = 0; e < m; ++e) {
            const float* hp = h + (long)l[e] * FEAT + f0;
            float4 b0 = *reinterpret_cast<const float4*>(hp);
            float4 b1 = *reinterpret_cast<const float4*>(hp + 4);
            acc[0] += b0.x; acc[1] += b0.y; acc[2] += b0.z; acc[3] += b0.w;
            acc[4] += b1.x; acc[5] += b1.y; acc[6] += b1.z; acc[7] += b1.w;
        }
        float4 a0 = {acc[0] * inv, acc[1] * inv, acc[2] * inv, acc[3] * inv};
        float4 a1 = {acc[4] * inv, acc[5] * inv, acc[6] * inv, acc[7] * inv};
        *reinterpret_cast<float4*>(&v[ln][f0])     = a0;
        *reinterpret_cast<float4*>(&v[ln][f0 + 4]) = a1;
        const float* hn = h + (long)n * FEAT + f0;
        *reinterpret_cast<float4*>(&v[ln][64 + f0])     = *reinterpret_cast<const float4*>(hn);
        *reinterpret_cast<float4*>(&v[ln][64 + f0 + 4]) = *reinterpret_cast<const float4*>(hn + 4);
    }
    __syncthreads();
    const int jg = tid & 15, lg = tid >> 4;
    const int j0 = jg * 8;
    // P1: r1 (K=128)
    {
        float A0[8], A1[8];
        #pragma unroll
        for (int c = 0; c < 8; ++c) { A0[c] = bl1[j0 + c]; A1[c] = A0[c]; }
        #pragma unroll 4
        for (int k = 0; k < 128; ++k) {
            float4 w0 = *reinterpret_cast<const float4*>(Ws1 + k * 128 + j0);
            float4 w1 = *reinterpret_cast<const float4*>(Ws1 + k * 128 + j0 + 4);
            float a = v[lg][k], b = v[lg + 16][k];
            A0[0] += a * w0.x; A0[1] += a * w0.y; A0[2] += a * w0.z; A0[3] += a * w0.w;
            A0[4] += a * w1.x; A0[5] += a * w1.y; A0[6] += a * w1.z; A0[7] += a * w1.w;
            A1[0] += b * w0.x; A1[1] += b * w0.y; A1[2] += b * w0.z; A1[3] += b * w0.w;
            A1[4] += b * w1.x; A1[5] += b * w1.y; A1[6] += b * w1.z; A1[7] += b * w1.w;
        }
        float4 o;
        o = {fmaxf(A0[0],0.f), fmaxf(A0[1],0.f), fmaxf(A0[2],0.f), fmaxf(A0[3],0.f)};
        *reinterpret_cast<float4*>(&rr[lg][j0]) = o;
        o = {fmaxf(A0[4],0.f), fmaxf(A0[5],0.f), fmaxf(A0[6],0.f), fmaxf(A0[7],0.f)};
        *reinterpret_cast<float4*>(&rr[lg][j0 + 4]) = o;
        o = {fmaxf(A1[0],0.f), fmaxf(A1[1],0.f), fmaxf(A1[2],0.f), fmaxf(A1[3],0.f)};
        *reinterpret_cast<float4*>(&rr[lg + 16][j0]) = o;
        o = {fmaxf(A1[4],0.f), fmaxf(A1[5],0.f), fmaxf(A1[6],0.f), fmaxf(A1[7],0.f)};
        *reinterpret_cast<float4*>(&rr[lg + 16][j0 + 4]) = o;
    }
    // P2: t (K=64, input = h part of v)
    {
        float A0[8], A1[8];
        #pragma unroll
        for (int c = 0; c < 8; ++c) { A0[c] = bf1[j0 + c]; A1[c] = A0[c]; }
        #pragma unroll 4
        for (int k = 0; k < 64; ++k) {
            float4 w0 = *reinterpret_cast<const float4*>(Wf1 + k * 128 + j0);
            float4 w1 = *reinterpret_cast<const float4*>(Wf1 + k * 128 + j0 + 4);
            float a = v[lg][64 + k], b = v[lg + 16][64 + k];
            A0[0] += a * w0.x; A0[1] += a * w0.y; A0[2] += a * w0.z; A0[3] += a * w0.w;
            A0[4] += a * w1.x; A0[5] += a * w1.y; A0[6] += a * w1.z; A0[7] += a * w1.w;
            A1[0] += b * w0.x; A1[1] += b * w0.y; A1[2] += b * w0.z; A1[3] += b * w0.w;
            A1[4] += b * w1.x; A1[5] += b * w1.y; A1[6] += b * w1.z; A1[7] += b * w1.w;
        }
        float4 o;
        o = {fmaxf(A0[0],0.f), fmaxf(A0[1],0.f), fmaxf(A0[2],0.f), fmaxf(A0[3],0.f)};
        *reinterpret_cast<float4*>(&tt[lg][j0]) = o;
        o = {fmaxf(A0[4],0.f), fmaxf(A0[5],0.f), fmaxf(A0[6],0.f), fmaxf(A0[7],0.f)};
        *reinterpret_cast<float4*>(&tt[lg][j0 + 4]) = o;
        o = {fmaxf(A1[0],0.f), fmaxf(A1[1],0.f), fmaxf(A1[2],0.f), fmaxf(A1[3],0.f)};
        *reinterpret_cast<float4*>(&tt[lg + 16][j0]) = o;
        o = {fmaxf(A1[4],0.f), fmaxf(A1[5],0.f), fmaxf(A1[6],0.f), fmaxf(A1[7],0.f)};
        *reinterpret_cast<float4*>(&tt[lg + 16][j0 + 4]) = o;
    }
    __syncthreads();
    // P3: xs = tt @ Wf2 + bf2 (64 cols, 4 cols/thread)
    {
        const int j4 = jg * 4;
        float X0[4], X1[4];
        #pragma unroll
        for (int c = 0; c < 4; ++c) { X0[c] = bf2[j4 + c]; X1[c] = X0[c]; }
        #pragma unroll 4
        for (int k = 0; k < 128; ++k) {
            float4 w = *reinterpret_cast<const float4*>(Wf2 + k * 64 + j4);
            float a = tt[lg][k], b = tt[lg + 16][k];
            X0[0] += a * w.x; X0[1] += a * w.y; X0[2] += a * w.z; X0[3] += a * w.w;
            X1[0] += b * w.x; X1[1] += b * w.y; X1[2] += b * w.z; X1[3] += b * w.w;
        }
        float4 o0 = {X0[0], X0[1], X0[2], X0[3]};
        float4 o1 = {X1[0], X1[1], X1[2], X1[3]};
        *reinterpret_cast<float4*>(&xsL[lg][j4])      = o0;
        *reinterpret_cast<float4*>(&xsL[lg + 16][j4]) = o1;
    }
    __syncthreads();
    // P4: [pl|q'] = rr @ Wc2 ; epilogue
    {
        float P0[8], P1v[8];
        #pragma unroll
        for (int c = 0; c < 8; ++c) { P0[c] = 0.0f; P1v[c] = 0.0f; }
        #pragma unroll 4
        for (int k = 0; k < 128; ++k) {
            float4 w0 = *reinterpret_cast<const float4*>(Wc2 + k * 128 + j0);
            float4 w1 = *reinterpret_cast<const float4*>(Wc2 + k * 128 + j0 + 4);
            float a = rr[lg][k], b = rr[lg + 16][k];
            P0[0] += a * w0.x; P0[1] += a * w0.y; P0[2] += a * w0.z; P0[3] += a * w0.w;
            P0[4] += a * w1.x; P0[5] += a * w1.y; P0[6] += a * w1.z; P0[7] += a * w1.w;
            P1v[0] += b * w0.x; P1v[1] += b * w0.y; P1v[2] += b * w0.z; P1v[3] += b * w0.w;
            P1v[4] += b * w1.x; P1v[5] += b * w1.y; P1v[6] += b * w1.z; P1v[7] += b * w1.w;
        }
        const int n0 = nb + lg, n1 = nb + lg + 16;
        if (jg < 8) {                                 // pl cols j0..j0+7
            float4 o;
            o = {P0[0], P0[1], P0[2], P0[3]};
            *reinterpret_cast<float4*>(pl + (long)n0 * FEAT + j0) = o;
            o = {P0[4], P0[5], P0[6], P0[7]};
            *reinterpret_cast<float4*>(pl + (long)n0 * FEAT + j0 + 4) = o;
            o = {P1v[0], P1v[1], P1v[2], P1v[3]};
            *reinterpret_cast<float4*>(pl + (long)n1 * FEAT + j0) = o;
            o = {P1v[4], P1v[5], P1v[6], P1v[7]};
            *reinterpret_cast<float4*>(pl + (long)n1 * FEAT + j0 + 4) = o;
        } else {                                      // q cols c0..c0+7
            const int c0 = j0 - 64;
            float4 o;
            o = {P0[0] + bl2[c0+0] + xsL[lg][c0+0], P0[1] + bl2[c0+1] + xsL[lg][c0+1],
                 P0[2] + bl2[c0+2] + xsL[lg][c0+2], P0[3] + bl2[c0+3] + xsL[lg][c0+3]};
            *reinterpret_cast<float4*>(q + (long)n0 * FEAT + c0) = o;
            o = {P0[4] + bl2[c0+4] + xsL[lg][c0+4], P0[5] + bl2[c0+5] + xsL[lg][c0+5],
                 P0[6] + bl2[c0+6] + xsL[lg][c0+6], P0[7] + bl2[c0+7] + xsL[lg][c0+7]};
            *reinterpret_cast<float4*>(q + (long)n0 * FEAT + c0 + 4) = o;
            o = {P1v[0] + bl2[c0+0] + xsL[lg+16][c0+0], P1v[1] + bl2[c0+1] + xsL[lg+16][c0+1],
                 P1v[2] + bl2[c0+2] + xsL[lg+16][c0+2], P1v[3] + bl2[c0+3] + xsL[lg+16][c0+3]};
            *reinterpret_cast<float4*>(q + (long)n1 * FEAT + c0) = o;
            o = {P1v[4] + bl2[c0+4] + xsL[lg+16][c0+4], P1v[5] + bl2[c0+5] + xsL[lg+16][c0+5],
                 P1v[6] + bl2[c0+6] + xsL[lg+16][c0+6], P1v[7] + bl2[c0+7] + xsL[lg+16][c0+7]};
            *reinterpret_cast<float4*>(q + (long)n1 * FEAT + c0 + 4) = o;
        }
    }
}

// ---------------- gather + Euler epilogue ----------------
__global__ __launch_bounds__(256)
void epi_kernel(const float* __restrict__ pl, const float* __restrict__ q,
                const int* __restrict__ lists, const int* __restrict__ cnt,
                const float* __restrict__ degf, const float* __restrict__ hcur,
                const float* __restrict__ tspan, int step,
                float* __restrict__ hnext) {
    const int tid = threadIdx.x;
    const int ln = tid >> 3, sub = tid & 7;
    const int n = blockIdx.x * 32 + ln;
    const int f0 = sub * 8;
    const int m = cnt[n];
    const int* l = lists + (long)n * CAP;
    const float inv = 1.0f / degf[n];
    float acc[8] = {0, 0, 0, 0, 0, 0, 0, 0};
    for (int e = 0; e < m; ++e) {
        const float* pp = pl + (long)l[e] * FEAT + f0;
        float4 b0 = *reinterpret_cast<const float4*>(pp);
        float4 b1 = *reinterpret_cast<const float4*>(pp + 4);
        acc[0] += b0.x; acc[1] += b0.y; acc[2] += b0.z; acc[3] += b0.w;
        acc[4] += b1.x; acc[5] += b1.y; acc[6] += b1.z; acc[7] += b1.w;
    }
    const float dt = tspan[step + 1] - tspan[step];
    float4 q0 = *reinterpret_cast<const float4*>(q + (long)n * FEAT + f0);
    float4 q1 = *reinterpret_cast<const float4*>(q + (long)n * FEAT + f0 + 4);
    float4 h0 = *reinterpret_cast<const float4*>(hcur + (long)n * FEAT + f0);
    float4 h1 = *reinterpret_cast<const float4*>(hcur + (long)n * FEAT + f0 + 4);
    float qa[8] = {q0.x, q0.y, q0.z, q0.w, q1.x, q1.y, q1.z, q1.w};
    float ha[8] = {h0.x, h0.y, h0.z, h0.w, h1.x, h1.y, h1.z, h1.w};
    float oa[8];
    #pragma unroll
    for (int c = 0; c < 8; ++c) {
        float s = qa[c] + acc[c] * inv;
        s = fminf(fmaxf(s, -1000.0f), 1000.0f);
        oa[c] = ha[c] + dt * s;
    }
    float4 o0 = {oa[0], oa[1], oa[2], oa[3]};
    float4 o1 = {oa[4], oa[5], oa[6], oa[7]};
    *reinterpret_cast<float4*>(hnext + (long)n * FEAT + f0)     = o0;
    *reinterpret_cast<float4*>(hnext + (long)n * FEAT + f0 + 4) = o1;
}

extern "C" void kernel_launch(void* const* d_in, const int* in_sizes, int n_in,
                              void* d_out, int out_size, void* d_ws, size_t ws_size,
                              hipStream_t stream) {
    const float* tspan = (const float*)d_in[0];
    const float* x     = (const float*)d_in[1];
    const float* adj   = (const float*)d_in[2];
    const float* We1   = (const float*)d_in[3];
    const float* be1   = (const float*)d_in[4];
    const float* We2   = (const float*)d_in[5];
    const float* be2   = (const float*)d_in[6];
    const float* Wf1   = (const float*)d_in[7];
    const float* bf1   = (const float*)d_in[8];
    const float* Wf2   = (const float*)d_in[9];
    const float* bf2   = (const float*)d_in[10];
    const float* Wl1   = (const float*)d_in[11];
    const float* bl1   = (const float*)d_in[12];
    const float* Wr1   = (const float*)d_in[13];
    const float* Wl2   = (const float*)d_in[14];
    const float* bl2   = (const float*)d_in[15];
    const float* Wr2   = (const float*)d_in[16];
    float* out = (float*)d_out;

    // workspace layout (bytes)
    char* ws = (char*)d_ws;
    int*   plist = (int*)  (ws + 0);           // 8000*16*12*4 = 6,144,000
    int*   pcnt  = (int*)  (ws + 6144000);     // 16*8000*4    =   512,000
    int*   lists = (int*)  (ws + 6656000);     // 8000*64*4    = 2,048,000
    int*   cnt   = (int*)  (ws + 8704000);     // 32,000
    float* degf  = (float*)(ws + 8736000);     // 32,000
    float* Ws1   = (float*)(ws + 8768000);     // 65,536
    float* Wc2   = (float*)(ws + 8833536);     // 65,536
    float* pl    = (float*)(ws + 8899072);     // 2,048,000
    float* q     = (float*)(ws + 10947072);    // 2,048,000
    // total 12,995,072 bytes

    scan_adj_kernel<<<512, 256, 0, stream>>>(adj, pcnt, plist);
    concat_kernel<<<160, 256, 0, stream>>>(pcnt, plist, cnt, lists, degf,
                                           Wl1, Wr1, Wl2, Wr2, Ws1, Wc2);
    init_enc_kernel<<<500, 256, 0, stream>>>(x, We1, be1, We2, be2, out);

    for (int s = 0; s < 3; ++s) {
        const float* hcur  = out + (long)s       * N_NODES * FEAT;
        float*       hnext = out + (long)(s + 1) * N_NODES * FEAT;
        sageproj_kernel<<<250, 256, 0, stream>>>(hcur, lists, cnt, degf,
                                                 Ws1, bl1, Wc2, bl2,
                                                 Wf1, bf1, Wf2, bf2, pl, q);
        epi_kernel<<<250, 256, 0, stream>>>(pl, q, lists, cnt, degf, hcur, tspan, s, hnext);
    }
}

// Round 5
// 300.199 us; speedup vs baseline: 1.2189x; 1.2189x over previous
//
#include <hip/hip_runtime.h>

#define N_NODES 8000
#define FEAT 64
#define HID 128
#define LOOKBACK 12
#define CAP 64

// ---------------- adjacency pattern extraction (atomic, fast) ----------------
__global__ __launch_bounds__(256)
void build_adj_kernel(const float* __restrict__ adj, int* __restrict__ cnt,
                      int* __restrict__ lists) {
    long q = (long)blockIdx.x * 256 + threadIdx.x;           // float4 index
    const long NQ = (long)N_NODES * N_NODES / 4;
    if (q >= NQ) return;
    int i  = (int)(q / (N_NODES / 4));
    int j0 = (int)(q % (N_NODES / 4)) * 4;
    float4 w = *reinterpret_cast<const float4*>(adj + (long)i * N_NODES + j0);
    float wv[4] = {w.x, w.y, w.z, w.w};
    #pragma unroll
    for (int c = 0; c < 4; ++c) {
        if (wv[c] != 0.0f) {
            int j = j0 + c;
            int p = atomicAdd(&cnt[j], 1);
            if (p < CAP) lists[(long)j * CAP + p] = i;       // edge i -> j
        }
    }
}

// ---------------- canonicalize: wave-bitonic sort per node + deg + weights ----
// blocks [0,2000): 4 waves/block, one node per wave, 64-lane bitonic sort.
// blocks [2000,2128): stack weight matrices.
__global__ __launch_bounds__(256)
void prep_kernel(int* __restrict__ cnt, int* __restrict__ lists,
                 float* __restrict__ degf,
                 const float* __restrict__ Wl1, const float* __restrict__ Wr1,
                 const float* __restrict__ Wl2, const float* __restrict__ Wr2,
                 float* __restrict__ Ws1, float* __restrict__ Wc2) {
    if (blockIdx.x < 2000) {
        const int wv   = threadIdx.x >> 6;
        const int lane = threadIdx.x & 63;
        const int n = blockIdx.x * 4 + wv;
        int m = cnt[n];
        if (m > CAP) m = CAP;
        int v = (lane < m) ? lists[(long)n * CAP + lane] : 0x7FFFFFFF;
        // 64-lane bitonic sort, ascending
        #pragma unroll
        for (int k = 2; k <= 64; k <<= 1) {
            #pragma unroll
            for (int j = k >> 1; j > 0; j >>= 1) {
                int other = __shfl_xor(v, j);
                bool up    = ((lane & k) == 0);
                bool lower = ((lane & j) == 0);
                bool keepMin = (lower == up);
                int mn = v < other ? v : other;
                int mx = v < other ? other : v;
                v = keepMin ? mn : mx;
            }
        }
        lists[(long)n * CAP + lane] = v;
        if (lane == 0) {
            cnt[n]  = m;
            degf[n] = (float)(m > 0 ? m : 1);
        }
    } else {
        int u = (blockIdx.x - 2000) * 256 + threadIdx.x;
        if (u < 128 * 128) {            // Ws1[k][j] = [Wl1;Wr1] row-stacked
            int k = u >> 7, j = u & 127;
            Ws1[u] = (k < 64) ? Wl1[k * 128 + j] : Wr1[(k - 64) * 128 + j];
        } else if (u < 2 * 128 * 128) { // Wc2[k][j] = [Wl2 | Wr2] col-stacked
            int w = u - 128 * 128;
            int k = w >> 7, j = w & 127;
            Wc2[w] = (j < 64) ? Wl2[k * 64 + j] : Wr2[k * 64 + (j - 64)];
        }
    }
}

// ---------------- init encoder: x[L,N,F] -> x0[N,F], 4 elems/thread ----------------
__global__ __launch_bounds__(256)
void init_enc_kernel(const float* __restrict__ x, const float* __restrict__ We1,
                     const float* __restrict__ be1, const float* __restrict__ We2,
                     const float* __restrict__ be2, float* __restrict__ out0) {
    __shared__ float sW1T[HID * LOOKBACK];   // [h][l]
    __shared__ float sB1[HID];
    __shared__ float sW2[HID];
    for (int e = threadIdx.x; e < HID * LOOKBACK; e += 256) {
        int l = e / HID, h = e % HID;
        sW1T[h * LOOKBACK + l] = We1[e];
    }
    for (int e = threadIdx.x; e < HID; e += 256) { sB1[e] = be1[e]; sW2[e] = We2[e]; }
    __syncthreads();
    int g = (blockIdx.x * 256 + threadIdx.x) * 4;
    if (g >= N_NODES * FEAT) return;
    float xv[4][LOOKBACK];
    #pragma unroll
    for (int l = 0; l < LOOKBACK; ++l) {
        float4 v = *reinterpret_cast<const float4*>(x + (long)l * N_NODES * FEAT + g);
        xv[0][l] = v.x; xv[1][l] = v.y; xv[2][l] = v.z; xv[3][l] = v.w;
    }
    float b2 = be2[0];
    float acc[4] = {b2, b2, b2, b2};
    for (int h = 0; h < HID; ++h) {
        float s0 = sB1[h], s1 = s0, s2 = s0, s3 = s0;
        #pragma unroll
        for (int l = 0; l < LOOKBACK; ++l) {
            float w = sW1T[h * LOOKBACK + l];
            s0 += xv[0][l] * w; s1 += xv[1][l] * w;
            s2 += xv[2][l] * w; s3 += xv[3][l] * w;
        }
        float w2 = sW2[h];
        acc[0] += fmaxf(s0, 0.0f) * w2; acc[1] += fmaxf(s1, 0.0f) * w2;
        acc[2] += fmaxf(s2, 0.0f) * w2; acc[3] += fmaxf(s3, 0.0f) * w2;
    }
    float4 o = {acc[0], acc[1], acc[2], acc[3]};
    *reinterpret_cast<float4*>(out0 + g) = o;
}

// ---------------- fused SAGE1 + proj + selfMLP ----------------
__global__ __launch_bounds__(256)
void sageproj_kernel(const float* __restrict__ h, const int* __restrict__ lists,
                     const int* __restrict__ cnt, const float* __restrict__ degf,
                     const float* __restrict__ Ws1, const float* __restrict__ bl1,
                     const float* __restrict__ Wc2, const float* __restrict__ bl2,
                     const float* __restrict__ Wf1, const float* __restrict__ bf1,
                     const float* __restrict__ Wf2, const float* __restrict__ bf2,
                     float* __restrict__ pl, float* __restrict__ q) {
    __shared__ float v[32][132];     // [node][k]: k<64 aggr, k>=64 h row
    __shared__ float rr[32][132];    // r1
    __shared__ float tt[32][132];    // t = relu(h@Wf1+bf1)
    __shared__ float xsL[32][68];    // xs
    const int tid = threadIdx.x;
    const int nb = blockIdx.x * 32;
    {   // gather: 8 threads/node, 8 feats each
        const int ln = tid >> 3, sub = tid & 7;
        const int n = nb + ln;
        const int f0 = sub * 8;
        const int m = cnt[n];
        const int* l = lists + (long)n * CAP;
        const float inv = 1.0f / degf[n];
        float acc[8] = {0, 0, 0, 0, 0, 0, 0, 0};
        for (int e = 0; e < m; ++e) {
            const float* hp = h + (long)l[e] * FEAT + f0;
            float4 b0 = *reinterpret_cast<const float4*>(hp);
            float4 b1 = *reinterpret_cast<const float4*>(hp + 4);
            acc[0] += b0.x; acc[1] += b0.y; acc[2] += b0.z; acc[3] += b0.w;
            acc[4] += b1.x; acc[5] += b1.y; acc[6] += b1.z; acc[7] += b1.w;
        }
        float4 a0 = {acc[0] * inv, acc[1] * inv, acc[2] * inv, acc[3] * inv};
        float4 a1 = {acc[4] * inv, acc[5] * inv, acc[6] * inv, acc[7] * inv};
        *reinterpret_cast<float4*>(&v[ln][f0])     = a0;
        *reinterpret_cast<float4*>(&v[ln][f0 + 4]) = a1;
        const float* hn = h + (long)n * FEAT + f0;
        *reinterpret_cast<float4*>(&v[ln][64 + f0])     = *reinterpret_cast<const float4*>(hn);
        *reinterpret_cast<float4*>(&v[ln][64 + f0 + 4]) = *reinterpret_cast<const float4*>(hn + 4);
    }
    __syncthreads();
    const int jg = tid & 15, lg = tid >> 4;
    const int j0 = jg * 8;
    // P1: r1 (K=128)
    {
        float A0[8], A1[8];
        #pragma unroll
        for (int c = 0; c < 8; ++c) { A0[c] = bl1[j0 + c]; A1[c] = A0[c]; }
        #pragma unroll 4
        for (int k = 0; k < 128; ++k) {
            float4 w0 = *reinterpret_cast<const float4*>(Ws1 + k * 128 + j0);
            float4 w1 = *reinterpret_cast<const float4*>(Ws1 + k * 128 + j0 + 4);
            float a = v[lg][k], b = v[lg + 16][k];
            A0[0] += a * w0.x; A0[1] += a * w0.y; A0[2] += a * w0.z; A0[3] += a * w0.w;
            A0[4] += a * w1.x; A0[5] += a * w1.y; A0[6] += a * w1.z; A0[7] += a * w1.w;
            A1[0] += b * w0.x; A1[1] += b * w0.y; A1[2] += b * w0.z; A1[3] += b * w0.w;
            A1[4] += b * w1.x; A1[5] += b * w1.y; A1[6] += b * w1.z; A1[7] += b * w1.w;
        }
        float4 o;
        o = {fmaxf(A0[0],0.f), fmaxf(A0[1],0.f), fmaxf(A0[2],0.f), fmaxf(A0[3],0.f)};
        *reinterpret_cast<float4*>(&rr[lg][j0]) = o;
        o = {fmaxf(A0[4],0.f), fmaxf(A0[5],0.f), fmaxf(A0[6],0.f), fmaxf(A0[7],0.f)};
        *reinterpret_cast<float4*>(&rr[lg][j0 + 4]) = o;
        o = {fmaxf(A1[0],0.f), fmaxf(A1[1],0.f), fmaxf(A1[2],0.f), fmaxf(A1[3],0.f)};
        *reinterpret_cast<float4*>(&rr[lg + 16][j0]) = o;
        o = {fmaxf(A1[4],0.f), fmaxf(A1[5],0.f), fmaxf(A1[6],0.f), fmaxf(A1[7],0.f)};
        *reinterpret_cast<float4*>(&rr[lg + 16][j0 + 4]) = o;
    }
    // P2: t (K=64, input = h part of v)
    {
        float A0[8], A1[8];
        #pragma unroll
        for (int c = 0; c < 8; ++c) { A0[c] = bf1[j0 + c]; A1[c] = A0[c]; }
        #pragma unroll 4
        for (int k = 0; k < 64; ++k) {
            float4 w0 = *reinterpret_cast<const float4*>(Wf1 + k * 128 + j0);
            float4 w1 = *reinterpret_cast<const float4*>(Wf1 + k * 128 + j0 + 4);
            float a = v[lg][64 + k], b = v[lg + 16][64 + k];
            A0[0] += a * w0.x; A0[1] += a * w0.y; A0[2] += a * w0.z; A0[3] += a * w0.w;
            A0[4] += a * w1.x; A0[5] += a * w1.y; A0[6] += a * w1.z; A0[7] += a * w1.w;
            A1[0] += b * w0.x; A1[1] += b * w0.y; A1[2] += b * w0.z; A1[3] += b * w0.w;
            A1[4] += b * w1.x; A1[5] += b * w1.y; A1[6] += b * w1.z; A1[7] += b * w1.w;
        }
        float4 o;
        o = {fmaxf(A0[0],0.f), fmaxf(A0[1],0.f), fmaxf(A0[2],0.f), fmaxf(A0[3],0.f)};
        *reinterpret_cast<float4*>(&tt[lg][j0]) = o;
        o = {fmaxf(A0[4],0.f), fmaxf(A0[5],0.f), fmaxf(A0[6],0.f), fmaxf(A0[7],0.f)};
        *reinterpret_cast<float4*>(&tt[lg][j0 + 4]) = o;
        o = {fmaxf(A1[0],0.f), fmaxf(A1[1],0.f), fmaxf(A1[2],0.f), fmaxf(A1[3],0.f)};
        *reinterpret_cast<float4*>(&tt[lg + 16][j0]) = o;
        o = {fmaxf(A1[4],0.f), fmaxf(A1[5],0.f), fmaxf(A1[6],0.f), fmaxf(A1[7],0.f)};
        *reinterpret_cast<float4*>(&tt[lg + 16][j0 + 4]) = o;
    }
    __syncthreads();
    // P3: xs = tt @ Wf2 + bf2 (64 cols, 4 cols/thread)
    {
        const int j4 = jg * 4;
        float X0[4], X1[4];
        #pragma unroll
        for (int c = 0; c < 4; ++c) { X0[c] = bf2[j4 + c]; X1[c] = X0[c]; }
        #pragma unroll 4
        for (int k = 0; k < 128; ++k) {
            float4 w = *reinterpret_cast<const float4*>(Wf2 + k * 64 + j4);
            float a = tt[lg][k], b = tt[lg + 16][k];
            X0[0] += a * w.x; X0[1] += a * w.y; X0[2] += a * w.z; X0[3] += a * w.w;
            X1[0] += b * w.x; X1[1] += b * w.y; X1[2] += b * w.z; X1[3] += b * w.w;
        }
        float4 o0 = {X0[0], X0[1], X0[2], X0[3]};
        float4 o1 = {X1[0], X1[1], X1[2], X1[3]};
        *reinterpret_cast<float4*>(&xsL[lg][j4])      = o0;
        *reinterpret_cast<float4*>(&xsL[lg + 16][j4]) = o1;
    }
    __syncthreads();
    // P4: [pl|q'] = rr @ Wc2 ; epilogue
    {
        float P0[8], P1v[8];
        #pragma unroll
        for (int c = 0; c < 8; ++c) { P0[c] = 0.0f; P1v[c] = 0.0f; }
        #pragma unroll 4
        for (int k = 0; k < 128; ++k) {
            float4 w0 = *reinterpret_cast<const float4*>(Wc2 + k * 128 + j0);
            float4 w1 = *reinterpret_cast<const float4*>(Wc2 + k * 128 + j0 + 4);
            float a = rr[lg][k], b = rr[lg + 16][k];
            P0[0] += a * w0.x; P0[1] += a * w0.y; P0[2] += a * w0.z; P0[3] += a * w0.w;
            P0[4] += a * w1.x; P0[5] += a * w1.y; P0[6] += a * w1.z; P0[7] += a * w1.w;
            P1v[0] += b * w0.x; P1v[1] += b * w0.y; P1v[2] += b * w0.z; P1v[3] += b * w0.w;
            P1v[4] += b * w1.x; P1v[5] += b * w1.y; P1v[6] += b * w1.z; P1v[7] += b * w1.w;
        }
        const int n0 = nb + lg, n1 = nb + lg + 16;
        if (jg < 8) {                                 // pl cols j0..j0+7
            float4 o;
            o = {P0[0], P0[1], P0[2], P0[3]};
            *reinterpret_cast<float4*>(pl + (long)n0 * FEAT + j0) = o;
            o = {P0[4], P0[5], P0[6], P0[7]};
            *reinterpret_cast<float4*>(pl + (long)n0 * FEAT + j0 + 4) = o;
            o = {P1v[0], P1v[1], P1v[2], P1v[3]};
            *reinterpret_cast<float4*>(pl + (long)n1 * FEAT + j0) = o;
            o = {P1v[4], P1v[5], P1v[6], P1v[7]};
            *reinterpret_cast<float4*>(pl + (long)n1 * FEAT + j0 + 4) = o;
        } else {                                      // q cols c0..c0+7
            const int c0 = j0 - 64;
            float4 o;
            o = {P0[0] + bl2[c0+0] + xsL[lg][c0+0], P0[1] + bl2[c0+1] + xsL[lg][c0+1],
                 P0[2] + bl2[c0+2] + xsL[lg][c0+2], P0[3] + bl2[c0+3] + xsL[lg][c0+3]};
            *reinterpret_cast<float4*>(q + (long)n0 * FEAT + c0) = o;
            o = {P0[4] + bl2[c0+4] + xsL[lg][c0+4], P0[5] + bl2[c0+5] + xsL[lg][c0+5],
                 P0[6] + bl2[c0+6] + xsL[lg][c0+6], P0[7] + bl2[c0+7] + xsL[lg][c0+7]};
            *reinterpret_cast<float4*>(q + (long)n0 * FEAT + c0 + 4) = o;
            o = {P1v[0] + bl2[c0+0] + xsL[lg+16][c0+0], P1v[1] + bl2[c0+1] + xsL[lg+16][c0+1],
                 P1v[2] + bl2[c0+2] + xsL[lg+16][c0+2], P1v[3] + bl2[c0+3] + xsL[lg+16][c0+3]};
            *reinterpret_cast<float4*>(q + (long)n1 * FEAT + c0) = o;
            o = {P1v[4] + bl2[c0+4] + xsL[lg+16][c0+4], P1v[5] + bl2[c0+5] + xsL[lg+16][c0+5],
                 P1v[6] + bl2[c0+6] + xsL[lg+16][c0+6], P1v[7] + bl2[c0+7] + xsL[lg+16][c0+7]};
            *reinterpret_cast<float4*>(q + (long)n1 * FEAT + c0 + 4) = o;
        }
    }
}

// ---------------- gather + Euler epilogue ----------------
__global__ __launch_bounds__(256)
void epi_kernel(const float* __restrict__ pl, const float* __restrict__ q,
                const int* __restrict__ lists, const int* __restrict__ cnt,
                const float* __restrict__ degf, const float* __restrict__ hcur,
                const float* __restrict__ tspan, int step,
                float* __restrict__ hnext) {
    const int tid = threadIdx.x;
    const int ln = tid >> 3, sub = tid & 7;
    const int n = blockIdx.x * 32 + ln;
    const int f0 = sub * 8;
    const int m = cnt[n];
    const int* l = lists + (long)n * CAP;
    const float inv = 1.0f / degf[n];
    float acc[8] = {0, 0, 0, 0, 0, 0, 0, 0};
    for (int e = 0; e < m; ++e) {
        const float* pp = pl + (long)l[e] * FEAT + f0;
        float4 b0 = *reinterpret_cast<const float4*>(pp);
        float4 b1 = *reinterpret_cast<const float4*>(pp + 4);
        acc[0] += b0.x; acc[1] += b0.y; acc[2] += b0.z; acc[3] += b0.w;
        acc[4] += b1.x; acc[5] += b1.y; acc[6] += b1.z; acc[7] += b1.w;
    }
    const float dt = tspan[step + 1] - tspan[step];
    float4 q0 = *reinterpret_cast<const float4*>(q + (long)n * FEAT + f0);
    float4 q1 = *reinterpret_cast<const float4*>(q + (long)n * FEAT + f0 + 4);
    float4 h0 = *reinterpret_cast<const float4*>(hcur + (long)n * FEAT + f0);
    float4 h1 = *reinterpret_cast<const float4*>(hcur + (long)n * FEAT + f0 + 4);
    float qa[8] = {q0.x, q0.y, q0.z, q0.w, q1.x, q1.y, q1.z, q1.w};
    float ha[8] = {h0.x, h0.y, h0.z, h0.w, h1.x, h1.y, h1.z, h1.w};
    float oa[8];
    #pragma unroll
    for (int c = 0; c < 8; ++c) {
        float s = qa[c] + acc[c] * inv;
        s = fminf(fmaxf(s, -1000.0f), 1000.0f);
        oa[c] = ha[c] + dt * s;
    }
    float4 o0 = {oa[0], oa[1], oa[2], oa[3]};
    float4 o1 = {oa[4], oa[5], oa[6], oa[7]};
    *reinterpret_cast<float4*>(hnext + (long)n * FEAT + f0)     = o0;
    *reinterpret_cast<float4*>(hnext + (long)n * FEAT + f0 + 4) = o1;
}

extern "C" void kernel_launch(void* const* d_in, const int* in_sizes, int n_in,
                              void* d_out, int out_size, void* d_ws, size_t ws_size,
                              hipStream_t stream) {
    const float* tspan = (const float*)d_in[0];
    const float* x     = (const float*)d_in[1];
    const float* adj   = (const float*)d_in[2];
    const float* We1   = (const float*)d_in[3];
    const float* be1   = (const float*)d_in[4];
    const float* We2   = (const float*)d_in[5];
    const float* be2   = (const float*)d_in[6];
    const float* Wf1   = (const float*)d_in[7];
    const float* bf1   = (const float*)d_in[8];
    const float* Wf2   = (const float*)d_in[9];
    const float* bf2   = (const float*)d_in[10];
    const float* Wl1   = (const float*)d_in[11];
    const float* bl1   = (const float*)d_in[12];
    const float* Wr1   = (const float*)d_in[13];
    const float* Wl2   = (const float*)d_in[14];
    const float* bl2   = (const float*)d_in[15];
    const float* Wr2   = (const float*)d_in[16];
    float* out = (float*)d_out;

    // workspace layout (bytes)
    char* ws = (char*)d_ws;
    int*   lists = (int*)  (ws + 0);           // 8000*64*4  = 2,048,000
    int*   cnt   = (int*)  (ws + 2048000);     // 32,000
    float* degf  = (float*)(ws + 2080000);     // 32,000
    float* Ws1   = (float*)(ws + 2112000);     // 65,536
    float* Wc2   = (float*)(ws + 2177536);     // 65,536
    float* pl    = (float*)(ws + 2243072);     // 2,048,000
    float* q     = (float*)(ws + 4291072);     // 2,048,000
    // total 6,339,072 bytes

    hipMemsetAsync(cnt, 0, N_NODES * sizeof(int), stream);
    build_adj_kernel<<<62500, 256, 0, stream>>>(adj, cnt, lists);
    prep_kernel<<<2128, 256, 0, stream>>>(cnt, lists, degf, Wl1, Wr1, Wl2, Wr2, Ws1, Wc2);
    init_enc_kernel<<<500, 256, 0, stream>>>(x, We1, be1, We2, be2, out);

    for (int s = 0; s < 3; ++s) {
        const float* hcur  = out + (long)s       * N_NODES * FEAT;
        float*       hnext = out + (long)(s + 1) * N_NODES * FEAT;
        sageproj_kernel<<<250, 256, 0, stream>>>(hcur, lists, cnt, degf,
                                                 Ws1, bl1, Wc2, bl2,
                                                 Wf1, bf1, Wf2, bf2, pl, q);
        epi_kernel<<<250, 256, 0, stream>>>(pl, q, lists, cnt, degf, hcur, tspan, s, hnext);
    }
}

// Round 6
// 250.376 us; speedup vs baseline: 1.4615x; 1.1990x over previous
//
#include <hip/hip_runtime.h>

#define N_NODES 8000
#define FEAT 64
#define HID 128
#define LOOKBACK 12
#define CAP 64

// ---------------- adjacency pattern extraction (atomic) ----------------
__global__ __launch_bounds__(256)
void build_adj_kernel(const float* __restrict__ adj, int* __restrict__ cnt,
                      int* __restrict__ lists) {
    long q = (long)blockIdx.x * 256 + threadIdx.x;           // float4 index
    const long NQ = (long)N_NODES * N_NODES / 4;
    if (q >= NQ) return;
    int i  = (int)(q / (N_NODES / 4));
    int j0 = (int)(q % (N_NODES / 4)) * 4;
    float4 w = *reinterpret_cast<const float4*>(adj + (long)i * N_NODES + j0);
    float wv[4] = {w.x, w.y, w.z, w.w};
    #pragma unroll
    for (int c = 0; c < 4; ++c) {
        if (wv[c] != 0.0f) {
            int j = j0 + c;
            int p = atomicAdd(&cnt[j], 1);
            if (p < CAP) lists[(long)j * CAP + p] = i;       // edge i -> j
        }
    }
}

// ---------------- canonicalize: wave-bitonic sort per node + deg + weights ----
__global__ __launch_bounds__(256)
void prep_kernel(int* __restrict__ cnt, int* __restrict__ lists,
                 float* __restrict__ degf,
                 const float* __restrict__ Wl1, const float* __restrict__ Wr1,
                 const float* __restrict__ Wl2, const float* __restrict__ Wr2,
                 float* __restrict__ Ws1, float* __restrict__ Wc2) {
    if (blockIdx.x < 2000) {
        const int wv   = threadIdx.x >> 6;
        const int lane = threadIdx.x & 63;
        const int n = blockIdx.x * 4 + wv;
        int m = cnt[n];
        if (m > CAP) m = CAP;
        int v = (lane < m) ? lists[(long)n * CAP + lane] : 0x7FFFFFFF;
        #pragma unroll
        for (int k = 2; k <= 64; k <<= 1) {
            #pragma unroll
            for (int j = k >> 1; j > 0; j >>= 1) {
                int other = __shfl_xor(v, j);
                bool up    = ((lane & k) == 0);
                bool lower = ((lane & j) == 0);
                bool keepMin = (lower == up);
                int mn = v < other ? v : other;
                int mx = v < other ? other : v;
                v = keepMin ? mn : mx;
            }
        }
        lists[(long)n * CAP + lane] = v;
        if (lane == 0) {
            cnt[n]  = m;
            degf[n] = (float)(m > 0 ? m : 1);
        }
    } else {
        int u = (blockIdx.x - 2000) * 256 + threadIdx.x;
        if (u < 128 * 128) {            // Ws1[k][j] = [Wl1;Wr1] row-stacked
            int k = u >> 7, j = u & 127;
            Ws1[u] = (k < 64) ? Wl1[k * 128 + j] : Wr1[(k - 64) * 128 + j];
        } else if (u < 2 * 128 * 128) { // Wc2[k][j] = [Wl2 | Wr2] col-stacked
            int w = u - 128 * 128;
            int k = w >> 7, j = w & 127;
            Wc2[w] = (j < 64) ? Wl2[k * 64 + j] : Wr2[k * 64 + (j - 64)];
        }
    }
}

// ---------------- init encoder: x[L,N,F] -> x0[N,F], 4 elems/thread ----------------
__global__ __launch_bounds__(256)
void init_enc_kernel(const float* __restrict__ x, const float* __restrict__ We1,
                     const float* __restrict__ be1, const float* __restrict__ We2,
                     const float* __restrict__ be2, float* __restrict__ out0) {
    __shared__ float sW1T[HID * LOOKBACK];   // [h][l]
    __shared__ float sB1[HID];
    __shared__ float sW2[HID];
    for (int e = threadIdx.x; e < HID * LOOKBACK; e += 256) {
        int l = e / HID, h = e % HID;
        sW1T[h * LOOKBACK + l] = We1[e];
    }
    for (int e = threadIdx.x; e < HID; e += 256) { sB1[e] = be1[e]; sW2[e] = We2[e]; }
    __syncthreads();
    int g = (blockIdx.x * 256 + threadIdx.x) * 4;
    if (g >= N_NODES * FEAT) return;
    float xv[4][LOOKBACK];
    #pragma unroll
    for (int l = 0; l < LOOKBACK; ++l) {
        float4 v = *reinterpret_cast<const float4*>(x + (long)l * N_NODES * FEAT + g);
        xv[0][l] = v.x; xv[1][l] = v.y; xv[2][l] = v.z; xv[3][l] = v.w;
    }
    float b2 = be2[0];
    float acc[4] = {b2, b2, b2, b2};
    for (int h = 0; h < HID; ++h) {
        float s0 = sB1[h], s1 = s0, s2 = s0, s3 = s0;
        #pragma unroll
        for (int l = 0; l < LOOKBACK; ++l) {
            float w = sW1T[h * LOOKBACK + l];
            s0 += xv[0][l] * w; s1 += xv[1][l] * w;
            s2 += xv[2][l] * w; s3 += xv[3][l] * w;
        }
        float w2 = sW2[h];
        acc[0] += fmaxf(s0, 0.0f) * w2; acc[1] += fmaxf(s1, 0.0f) * w2;
        acc[2] += fmaxf(s2, 0.0f) * w2; acc[3] += fmaxf(s3, 0.0f) * w2;
    }
    float4 o = {acc[0], acc[1], acc[2], acc[3]};
    *reinterpret_cast<float4*>(out0 + g) = o;
}

// ---------------- fused SAGE1 + proj + selfMLP (LDS-staged weights) ----------------
// 16 nodes/block, 500 blocks (2 blocks/CU, 2 waves/SIMD).
// thread: node ln = tid>>4, col group jg = tid&15, owns cols {4jg..4jg+3} and
// {64+4jg..} of the 128-wide phases (2-way LDS bank aliasing only => free).
__global__ __launch_bounds__(256)
void sageproj_kernel(const float* __restrict__ h, const int* __restrict__ lists,
                     const int* __restrict__ cnt, const float* __restrict__ degf,
                     const float* __restrict__ Ws1, const float* __restrict__ bl1,
                     const float* __restrict__ Wc2, const float* __restrict__ bl2,
                     const float* __restrict__ Wf1, const float* __restrict__ bf1,
                     const float* __restrict__ Wf2, const float* __restrict__ bf2,
                     float* __restrict__ pl, float* __restrict__ q) {
    __shared__ float v[16][132];     // [node][k]: k<64 aggr, k>=64 h row
    __shared__ float rr[16][132];    // r1
    __shared__ float tt[16][132];    // t = relu(h@Wf1+bf1)
    __shared__ float xsl[16][68];    // xs
    __shared__ float wbuf[64 * 128]; // 32 KB weight panel chunk
    const int tid = threadIdx.x;
    const int nb = blockIdx.x * 16;
    const int ln = tid >> 4, jg = tid & 15;
    const int n = nb + ln;
    const int c0 = jg * 4;
    {   // gather: 16 threads/node, 4 feats each
        const int f0 = c0;
        const int m = cnt[n];
        const int* l = lists + (long)n * CAP;
        const float inv = 1.0f / degf[n];
        float4 a = {0, 0, 0, 0};
        for (int e = 0; e < m; ++e) {
            float4 b = *reinterpret_cast<const float4*>(h + (long)l[e] * FEAT + f0);
            a.x += b.x; a.y += b.y; a.z += b.z; a.w += b.w;
        }
        float4 av = {a.x * inv, a.y * inv, a.z * inv, a.w * inv};
        *reinterpret_cast<float4*>(&v[ln][f0]) = av;
        *reinterpret_cast<float4*>(&v[ln][64 + f0]) =
            *reinterpret_cast<const float4*>(h + (long)n * FEAT + f0);
    }
    // ---- P1: rr = relu([aggr|h] @ Ws1 + bl1), K=128 in 2 chunks ----
    {
        float4 b0 = *reinterpret_cast<const float4*>(bl1 + c0);
        float4 b1 = *reinterpret_cast<const float4*>(bl1 + 64 + c0);
        float A0[4] = {b0.x, b0.y, b0.z, b0.w};
        float A1[4] = {b1.x, b1.y, b1.z, b1.w};
        for (int kc = 0; kc < 2; ++kc) {
            __syncthreads();                     // prev consumers done / v ready
            for (int e = tid; e < 2048; e += 256)
                *(reinterpret_cast<float4*>(wbuf) + e) =
                    *(reinterpret_cast<const float4*>(Ws1 + kc * 8192) + e);
            __syncthreads();
            #pragma unroll 4
            for (int k = 0; k < 64; ++k) {
                float a = v[ln][kc * 64 + k];
                float4 w0 = *reinterpret_cast<const float4*>(&wbuf[k * 128 + c0]);
                float4 w1 = *reinterpret_cast<const float4*>(&wbuf[k * 128 + 64 + c0]);
                A0[0] += a * w0.x; A0[1] += a * w0.y; A0[2] += a * w0.z; A0[3] += a * w0.w;
                A1[0] += a * w1.x; A1[1] += a * w1.y; A1[2] += a * w1.z; A1[3] += a * w1.w;
            }
        }
        float4 o0 = {fmaxf(A0[0],0.f), fmaxf(A0[1],0.f), fmaxf(A0[2],0.f), fmaxf(A0[3],0.f)};
        float4 o1 = {fmaxf(A1[0],0.f), fmaxf(A1[1],0.f), fmaxf(A1[2],0.f), fmaxf(A1[3],0.f)};
        *reinterpret_cast<float4*>(&rr[ln][c0]) = o0;
        *reinterpret_cast<float4*>(&rr[ln][64 + c0]) = o1;
    }
    // ---- P2: tt = relu(h @ Wf1 + bf1), K=64, one chunk ----
    {
        float4 b0 = *reinterpret_cast<const float4*>(bf1 + c0);
        float4 b1 = *reinterpret_cast<const float4*>(bf1 + 64 + c0);
        float A0[4] = {b0.x, b0.y, b0.z, b0.w};
        float A1[4] = {b1.x, b1.y, b1.z, b1.w};
        __syncthreads();
        for (int e = tid; e < 2048; e += 256)
            *(reinterpret_cast<float4*>(wbuf) + e) =
                *(reinterpret_cast<const float4*>(Wf1) + e);
        __syncthreads();
        #pragma unroll 4
        for (int k = 0; k < 64; ++k) {
            float a = v[ln][64 + k];
            float4 w0 = *reinterpret_cast<const float4*>(&wbuf[k * 128 + c0]);
            float4 w1 = *reinterpret_cast<const float4*>(&wbuf[k * 128 + 64 + c0]);
            A0[0] += a * w0.x; A0[1] += a * w0.y; A0[2] += a * w0.z; A0[3] += a * w0.w;
            A1[0] += a * w1.x; A1[1] += a * w1.y; A1[2] += a * w1.z; A1[3] += a * w1.w;
        }
        float4 o0 = {fmaxf(A0[0],0.f), fmaxf(A0[1],0.f), fmaxf(A0[2],0.f), fmaxf(A0[3],0.f)};
        float4 o1 = {fmaxf(A1[0],0.f), fmaxf(A1[1],0.f), fmaxf(A1[2],0.f), fmaxf(A1[3],0.f)};
        *reinterpret_cast<float4*>(&tt[ln][c0]) = o0;
        *reinterpret_cast<float4*>(&tt[ln][64 + c0]) = o1;
    }
    // ---- P3: xsl = tt @ Wf2 + bf2, K=128, 64 cols, one chunk (Wf2 = [128][64]) ----
    {
        float4 b0 = *reinterpret_cast<const float4*>(bf2 + c0);
        float X[4] = {b0.x, b0.y, b0.z, b0.w};
        __syncthreads();
        for (int e = tid; e < 2048; e += 256)
            *(reinterpret_cast<float4*>(wbuf) + e) =
                *(reinterpret_cast<const float4*>(Wf2) + e);
        __syncthreads();
        #pragma unroll 4
        for (int k = 0; k < 128; ++k) {
            float a = tt[ln][k];
            float4 w = *reinterpret_cast<const float4*>(&wbuf[k * 64 + c0]);
            X[0] += a * w.x; X[1] += a * w.y; X[2] += a * w.z; X[3] += a * w.w;
        }
        float4 o = {X[0], X[1], X[2], X[3]};
        *reinterpret_cast<float4*>(&xsl[ln][c0]) = o;
    }
    // ---- P4: [pl|q] = rr @ Wc2 (+ bl2 + xsl on q half), K=128 in 2 chunks ----
    {
        float P0[4] = {0, 0, 0, 0};
        float P1[4] = {0, 0, 0, 0};
        for (int kc = 0; kc < 2; ++kc) {
            __syncthreads();
            for (int e = tid; e < 2048; e += 256)
                *(reinterpret_cast<float4*>(wbuf) + e) =
                    *(reinterpret_cast<const float4*>(Wc2 + kc * 8192) + e);
            __syncthreads();
            #pragma unroll 4
            for (int k = 0; k < 64; ++k) {
                float a = rr[ln][kc * 64 + k];
                float4 w0 = *reinterpret_cast<const float4*>(&wbuf[k * 128 + c0]);
                float4 w1 = *reinterpret_cast<const float4*>(&wbuf[k * 128 + 64 + c0]);
                P0[0] += a * w0.x; P0[1] += a * w0.y; P0[2] += a * w0.z; P0[3] += a * w0.w;
                P1[0] += a * w1.x; P1[1] += a * w1.y; P1[2] += a * w1.z; P1[3] += a * w1.w;
            }
        }
        float4 op = {P0[0], P0[1], P0[2], P0[3]};
        *reinterpret_cast<float4*>(pl + (long)n * FEAT + c0) = op;
        float4 bv = *reinterpret_cast<const float4*>(bl2 + c0);
        float4 oq = {P1[0] + bv.x + xsl[ln][c0 + 0],
                     P1[1] + bv.y + xsl[ln][c0 + 1],
                     P1[2] + bv.z + xsl[ln][c0 + 2],
                     P1[3] + bv.w + xsl[ln][c0 + 3]};
        *reinterpret_cast<float4*>(q + (long)n * FEAT + c0) = oq;
    }
}

// ---------------- gather + Euler epilogue ----------------
__global__ __launch_bounds__(256)
void epi_kernel(const float* __restrict__ pl, const float* __restrict__ q,
                const int* __restrict__ lists, const int* __restrict__ cnt,
                const float* __restrict__ degf, const float* __restrict__ hcur,
                const float* __restrict__ tspan, int step,
                float* __restrict__ hnext) {
    const int tid = threadIdx.x;
    const int ln = tid >> 4, sub = tid & 15;
    const int n = blockIdx.x * 16 + ln;
    const int f0 = sub * 4;
    const int m = cnt[n];
    const int* l = lists + (long)n * CAP;
    const float inv = 1.0f / degf[n];
    float4 a = {0, 0, 0, 0};
    for (int e = 0; e < m; ++e) {
        float4 b = *reinterpret_cast<const float4*>(pl + (long)l[e] * FEAT + f0);
        a.x += b.x; a.y += b.y; a.z += b.z; a.w += b.w;
    }
    const float dt = tspan[step + 1] - tspan[step];
    float4 qv = *reinterpret_cast<const float4*>(q + (long)n * FEAT + f0);
    float4 hv = *reinterpret_cast<const float4*>(hcur + (long)n * FEAT + f0);
    float s0 = qv.x + a.x * inv, s1 = qv.y + a.y * inv;
    float s2 = qv.z + a.z * inv, s3 = qv.w + a.w * inv;
    s0 = fminf(fmaxf(s0, -1000.f), 1000.f); s1 = fminf(fmaxf(s1, -1000.f), 1000.f);
    s2 = fminf(fmaxf(s2, -1000.f), 1000.f); s3 = fminf(fmaxf(s3, -1000.f), 1000.f);
    float4 o = {hv.x + dt * s0, hv.y + dt * s1, hv.z + dt * s2, hv.w + dt * s3};
    *reinterpret_cast<float4*>(hnext + (long)n * FEAT + f0) = o;
}

extern "C" void kernel_launch(void* const* d_in, const int* in_sizes, int n_in,
                              void* d_out, int out_size, void* d_ws, size_t ws_size,
                              hipStream_t stream) {
    const float* tspan = (const float*)d_in[0];
    const float* x     = (const float*)d_in[1];
    const float* adj   = (const float*)d_in[2];
    const float* We1   = (const float*)d_in[3];
    const float* be1   = (const float*)d_in[4];
    const float* We2   = (const float*)d_in[5];
    const float* be2   = (const float*)d_in[6];
    const float* Wf1   = (const float*)d_in[7];
    const float* bf1   = (const float*)d_in[8];
    const float* Wf2   = (const float*)d_in[9];
    const float* bf2   = (const float*)d_in[10];
    const float* Wl1   = (const float*)d_in[11];
    const float* bl1   = (const float*)d_in[12];
    const float* Wr1   = (const float*)d_in[13];
    const float* Wl2   = (const float*)d_in[14];
    const float* bl2   = (const float*)d_in[15];
    const float* Wr2   = (const float*)d_in[16];
    float* out = (float*)d_out;

    // workspace layout (bytes)
    char* ws = (char*)d_ws;
    int*   lists = (int*)  (ws + 0);           // 8000*64*4  = 2,048,000
    int*   cnt   = (int*)  (ws + 2048000);     // 32,000
    float* degf  = (float*)(ws + 2080000);     // 32,000
    float* Ws1   = (float*)(ws + 2112000);     // 65,536
    float* Wc2   = (float*)(ws + 2177536);     // 65,536
    float* pl    = (float*)(ws + 2243072);     // 2,048,000
    float* q     = (float*)(ws + 4291072);     // 2,048,000
    // total 6,339,072 bytes

    hipMemsetAsync(cnt, 0, N_NODES * sizeof(int), stream);
    build_adj_kernel<<<62500, 256, 0, stream>>>(adj, cnt, lists);
    prep_kernel<<<2128, 256, 0, stream>>>(cnt, lists, degf, Wl1, Wr1, Wl2, Wr2, Ws1, Wc2);
    init_enc_kernel<<<500, 256, 0, stream>>>(x, We1, be1, We2, be2, out);

    for (int s = 0; s < 3; ++s) {
        const float* hcur  = out + (long)s       * N_NODES * FEAT;
        float*       hnext = out + (long)(s + 1) * N_NODES * FEAT;
        sageproj_kernel<<<500, 256, 0, stream>>>(hcur, lists, cnt, degf,
                                                 Ws1, bl1, Wc2, bl2,
                                                 Wf1, bf1, Wf2, bf2, pl, q);
        epi_kernel<<<500, 256, 0, stream>>>(pl, q, lists, cnt, degf, hcur, tspan, s, hnext);
    }
}

// Round 7
// 250.243 us; speedup vs baseline: 1.4622x; 1.0005x over previous
//
#include <hip/hip_runtime.h>

#define N_NODES 8000
#define FEAT 64
#define HID 128
#define LOOKBACK 12
#define CAP 64

// ---------------- zero the per-node counters (replaces pathological hipMemsetAsync) ----
__global__ __launch_bounds__(256)
void zero_cnt_kernel(int* __restrict__ cnt) {
    int g = blockIdx.x * 256 + threadIdx.x;
    if (g < N_NODES) cnt[g] = 0;
}

// ---------------- adjacency pattern extraction (atomic) ----------------
__global__ __launch_bounds__(256)
void build_adj_kernel(const float* __restrict__ adj, int* __restrict__ cnt,
                      int* __restrict__ lists) {
    long q = (long)blockIdx.x * 256 + threadIdx.x;           // float4 index
    const long NQ = (long)N_NODES * N_NODES / 4;
    if (q >= NQ) return;
    int i  = (int)(q / (N_NODES / 4));
    int j0 = (int)(q % (N_NODES / 4)) * 4;
    float4 w = *reinterpret_cast<const float4*>(adj + (long)i * N_NODES + j0);
    float wv[4] = {w.x, w.y, w.z, w.w};
    #pragma unroll
    for (int c = 0; c < 4; ++c) {
        if (wv[c] != 0.0f) {
            int j = j0 + c;
            int p = atomicAdd(&cnt[j], 1);
            if (p < CAP) lists[(long)j * CAP + p] = i;       // edge i -> j
        }
    }
}

// ---------------- canonicalize: wave-bitonic sort per node + deg + weights ----
__global__ __launch_bounds__(256)
void prep_kernel(int* __restrict__ cnt, int* __restrict__ lists,
                 float* __restrict__ degf,
                 const float* __restrict__ Wl1, const float* __restrict__ Wr1,
                 const float* __restrict__ Wl2, const float* __restrict__ Wr2,
                 float* __restrict__ Ws1, float* __restrict__ Wc2) {
    if (blockIdx.x < 2000) {
        const int wv   = threadIdx.x >> 6;
        const int lane = threadIdx.x & 63;
        const int n = blockIdx.x * 4 + wv;
        int m = cnt[n];
        if (m > CAP) m = CAP;
        int v = (lane < m) ? lists[(long)n * CAP + lane] : 0x7FFFFFFF;
        #pragma unroll
        for (int k = 2; k <= 64; k <<= 1) {
            #pragma unroll
            for (int j = k >> 1; j > 0; j >>= 1) {
                int other = __shfl_xor(v, j);
                bool up    = ((lane & k) == 0);
                bool lower = ((lane & j) == 0);
                bool keepMin = (lower == up);
                int mn = v < other ? v : other;
                int mx = v < other ? other : v;
                v = keepMin ? mn : mx;
            }
        }
        lists[(long)n * CAP + lane] = v;
        if (lane == 0) {
            cnt[n]  = m;
            degf[n] = (float)(m > 0 ? m : 1);
        }
    } else {
        int u = (blockIdx.x - 2000) * 256 + threadIdx.x;
        if (u < 128 * 128) {            // Ws1[k][j] = [Wl1;Wr1] row-stacked
            int k = u >> 7, j = u & 127;
            Ws1[u] = (k < 64) ? Wl1[k * 128 + j] : Wr1[(k - 64) * 128 + j];
        } else if (u < 2 * 128 * 128) { // Wc2[k][j] = [Wl2 | Wr2] col-stacked
            int w = u - 128 * 128;
            int k = w >> 7, j = w & 127;
            Wc2[w] = (j < 64) ? Wl2[k * 64 + j] : Wr2[k * 64 + (j - 64)];
        }
    }
}

// ---------------- init encoder: x[L,N,F] -> x0[N,F], 4 elems/thread ----------------
__global__ __launch_bounds__(256)
void init_enc_kernel(const float* __restrict__ x, const float* __restrict__ We1,
                     const float* __restrict__ be1, const float* __restrict__ We2,
                     const float* __restrict__ be2, float* __restrict__ out0) {
    __shared__ float sW1T[HID * LOOKBACK];   // [h][l]
    __shared__ float sB1[HID];
    __shared__ float sW2[HID];
    for (int e = threadIdx.x; e < HID * LOOKBACK; e += 256) {
        int l = e / HID, h = e % HID;
        sW1T[h * LOOKBACK + l] = We1[e];
    }
    for (int e = threadIdx.x; e < HID; e += 256) { sB1[e] = be1[e]; sW2[e] = We2[e]; }
    __syncthreads();
    int g = (blockIdx.x * 256 + threadIdx.x) * 4;
    if (g >= N_NODES * FEAT) return;
    float xv[4][LOOKBACK];
    #pragma unroll
    for (int l = 0; l < LOOKBACK; ++l) {
        float4 v = *reinterpret_cast<const float4*>(x + (long)l * N_NODES * FEAT + g);
        xv[0][l] = v.x; xv[1][l] = v.y; xv[2][l] = v.z; xv[3][l] = v.w;
    }
    float b2 = be2[0];
    float acc[4] = {b2, b2, b2, b2};
    for (int h = 0; h < HID; ++h) {
        float s0 = sB1[h], s1 = s0, s2 = s0, s3 = s0;
        #pragma unroll
        for (int l = 0; l < LOOKBACK; ++l) {
            float w = sW1T[h * LOOKBACK + l];
            s0 += xv[0][l] * w; s1 += xv[1][l] * w;
            s2 += xv[2][l] * w; s3 += xv[3][l] * w;
        }
        float w2 = sW2[h];
        acc[0] += fmaxf(s0, 0.0f) * w2; acc[1] += fmaxf(s1, 0.0f) * w2;
        acc[2] += fmaxf(s2, 0.0f) * w2; acc[3] += fmaxf(s3, 0.0f) * w2;
    }
    float4 o = {acc[0], acc[1], acc[2], acc[3]};
    *reinterpret_cast<float4*>(out0 + g) = o;
}

// ---------------- fused SAGE1 + proj + selfMLP (LDS-staged weights) ----------------
// 16 nodes/block, 500 blocks (2 blocks/CU, 2 waves/SIMD).
__global__ __launch_bounds__(256)
void sageproj_kernel(const float* __restrict__ h, const int* __restrict__ lists,
                     const int* __restrict__ cnt, const float* __restrict__ degf,
                     const float* __restrict__ Ws1, const float* __restrict__ bl1,
                     const float* __restrict__ Wc2, const float* __restrict__ bl2,
                     const float* __restrict__ Wf1, const float* __restrict__ bf1,
                     const float* __restrict__ Wf2, const float* __restrict__ bf2,
                     float* __restrict__ pl, float* __restrict__ q) {
    __shared__ float v[16][132];     // [node][k]: k<64 aggr, k>=64 h row
    __shared__ float rr[16][132];    // r1
    __shared__ float tt[16][132];    // t = relu(h@Wf1+bf1)
    __shared__ float xsl[16][68];    // xs
    __shared__ float wbuf[64 * 128]; // 32 KB weight panel chunk
    const int tid = threadIdx.x;
    const int nb = blockIdx.x * 16;
    const int ln = tid >> 4, jg = tid & 15;
    const int n = nb + ln;
    const int c0 = jg * 4;
    {   // gather: 16 threads/node, 4 feats each
        const int f0 = c0;
        const int m = cnt[n];
        const int* l = lists + (long)n * CAP;
        const float inv = 1.0f / degf[n];
        float4 a = {0, 0, 0, 0};
        for (int e = 0; e < m; ++e) {
            float4 b = *reinterpret_cast<const float4*>(h + (long)l[e] * FEAT + f0);
            a.x += b.x; a.y += b.y; a.z += b.z; a.w += b.w;
        }
        float4 av = {a.x * inv, a.y * inv, a.z * inv, a.w * inv};
        *reinterpret_cast<float4*>(&v[ln][f0]) = av;
        *reinterpret_cast<float4*>(&v[ln][64 + f0]) =
            *reinterpret_cast<const float4*>(h + (long)n * FEAT + f0);
    }
    // ---- P1: rr = relu([aggr|h] @ Ws1 + bl1), K=128 in 2 chunks ----
    {
        float4 b0 = *reinterpret_cast<const float4*>(bl1 + c0);
        float4 b1 = *reinterpret_cast<const float4*>(bl1 + 64 + c0);
        float A0[4] = {b0.x, b0.y, b0.z, b0.w};
        float A1[4] = {b1.x, b1.y, b1.z, b1.w};
        for (int kc = 0; kc < 2; ++kc) {
            __syncthreads();                     // prev consumers done / v ready
            for (int e = tid; e < 2048; e += 256)
                *(reinterpret_cast<float4*>(wbuf) + e) =
                    *(reinterpret_cast<const float4*>(Ws1 + kc * 8192) + e);
            __syncthreads();
            #pragma unroll 4
            for (int k = 0; k < 64; ++k) {
                float a = v[ln][kc * 64 + k];
                float4 w0 = *reinterpret_cast<const float4*>(&wbuf[k * 128 + c0]);
                float4 w1 = *reinterpret_cast<const float4*>(&wbuf[k * 128 + 64 + c0]);
                A0[0] += a * w0.x; A0[1] += a * w0.y; A0[2] += a * w0.z; A0[3] += a * w0.w;
                A1[0] += a * w1.x; A1[1] += a * w1.y; A1[2] += a * w1.z; A1[3] += a * w1.w;
            }
        }
        float4 o0 = {fmaxf(A0[0],0.f), fmaxf(A0[1],0.f), fmaxf(A0[2],0.f), fmaxf(A0[3],0.f)};
        float4 o1 = {fmaxf(A1[0],0.f), fmaxf(A1[1],0.f), fmaxf(A1[2],0.f), fmaxf(A1[3],0.f)};
        *reinterpret_cast<float4*>(&rr[ln][c0]) = o0;
        *reinterpret_cast<float4*>(&rr[ln][64 + c0]) = o1;
    }
    // ---- P2: tt = relu(h @ Wf1 + bf1), K=64, one chunk ----
    {
        float4 b0 = *reinterpret_cast<const float4*>(bf1 + c0);
        float4 b1 = *reinterpret_cast<const float4*>(bf1 + 64 + c0);
        float A0[4] = {b0.x, b0.y, b0.z, b0.w};
        float A1[4] = {b1.x, b1.y, b1.z, b1.w};
        __syncthreads();
        for (int e = tid; e < 2048; e += 256)
            *(reinterpret_cast<float4*>(wbuf) + e) =
                *(reinterpret_cast<const float4*>(Wf1) + e);
        __syncthreads();
        #pragma unroll 4
        for (int k = 0; k < 64; ++k) {
            float a = v[ln][64 + k];
            float4 w0 = *reinterpret_cast<const float4*>(&wbuf[k * 128 + c0]);
            float4 w1 = *reinterpret_cast<const float4*>(&wbuf[k * 128 + 64 + c0]);
            A0[0] += a * w0.x; A0[1] += a * w0.y; A0[2] += a * w0.z; A0[3] += a * w0.w;
            A1[0] += a * w1.x; A1[1] += a * w1.y; A1[2] += a * w1.z; A1[3] += a * w1.w;
        }
        float4 o0 = {fmaxf(A0[0],0.f), fmaxf(A0[1],0.f), fmaxf(A0[2],0.f), fmaxf(A0[3],0.f)};
        float4 o1 = {fmaxf(A1[0],0.f), fmaxf(A1[1],0.f), fmaxf(A1[2],0.f), fmaxf(A1[3],0.f)};
        *reinterpret_cast<float4*>(&tt[ln][c0]) = o0;
        *reinterpret_cast<float4*>(&tt[ln][64 + c0]) = o1;
    }
    // ---- P3: xsl = tt @ Wf2 + bf2, K=128, 64 cols, one chunk (Wf2 = [128][64]) ----
    {
        float4 b0 = *reinterpret_cast<const float4*>(bf2 + c0);
        float X[4] = {b0.x, b0.y, b0.z, b0.w};
        __syncthreads();
        for (int e = tid; e < 2048; e += 256)
            *(reinterpret_cast<float4*>(wbuf) + e) =
                *(reinterpret_cast<const float4*>(Wf2) + e);
        __syncthreads();
        #pragma unroll 4
        for (int k = 0; k < 128; ++k) {
            float a = tt[ln][k];
            float4 w = *reinterpret_cast<const float4*>(&wbuf[k * 64 + c0]);
            X[0] += a * w.x; X[1] += a * w.y; X[2] += a * w.z; X[3] += a * w.w;
        }
        float4 o = {X[0], X[1], X[2], X[3]};
        *reinterpret_cast<float4*>(&xsl[ln][c0]) = o;
    }
    // ---- P4: [pl|q] = rr @ Wc2 (+ bl2 + xsl on q half), K=128 in 2 chunks ----
    {
        float P0[4] = {0, 0, 0, 0};
        float P1[4] = {0, 0, 0, 0};
        for (int kc = 0; kc < 2; ++kc) {
            __syncthreads();
            for (int e = tid; e < 2048; e += 256)
                *(reinterpret_cast<float4*>(wbuf) + e) =
                    *(reinterpret_cast<const float4*>(Wc2 + kc * 8192) + e);
            __syncthreads();
            #pragma unroll 4
            for (int k = 0; k < 64; ++k) {
                float a = rr[ln][kc * 64 + k];
                float4 w0 = *reinterpret_cast<const float4*>(&wbuf[k * 128 + c0]);
                float4 w1 = *reinterpret_cast<const float4*>(&wbuf[k * 128 + 64 + c0]);
                P0[0] += a * w0.x; P0[1] += a * w0.y; P0[2] += a * w0.z; P0[3] += a * w0.w;
                P1[0] += a * w1.x; P1[1] += a * w1.y; P1[2] += a * w1.z; P1[3] += a * w1.w;
            }
        }
        float4 op = {P0[0], P0[1], P0[2], P0[3]};
        *reinterpret_cast<float4*>(pl + (long)n * FEAT + c0) = op;
        float4 bv = *reinterpret_cast<const float4*>(bl2 + c0);
        float4 oq = {P1[0] + bv.x + xsl[ln][c0 + 0],
                     P1[1] + bv.y + xsl[ln][c0 + 1],
                     P1[2] + bv.z + xsl[ln][c0 + 2],
                     P1[3] + bv.w + xsl[ln][c0 + 3]};
        *reinterpret_cast<float4*>(q + (long)n * FEAT + c0) = oq;
    }
}

// ---------------- gather + Euler epilogue ----------------
__global__ __launch_bounds__(256)
void epi_kernel(const float* __restrict__ pl, const float* __restrict__ q,
                const int* __restrict__ lists, const int* __restrict__ cnt,
                const float* __restrict__ degf, const float* __restrict__ hcur,
                const float* __restrict__ tspan, int step,
                float* __restrict__ hnext) {
    const int tid = threadIdx.x;
    const int ln = tid >> 4, sub = tid & 15;
    const int n = blockIdx.x * 16 + ln;
    const int f0 = sub * 4;
    const int m = cnt[n];
    const int* l = lists + (long)n * CAP;
    const float inv = 1.0f / degf[n];
    float4 a = {0, 0, 0, 0};
    for (int e = 0; e < m; ++e) {
        float4 b = *reinterpret_cast<const float4*>(pl + (long)l[e] * FEAT + f0);
        a.x += b.x; a.y += b.y; a.z += b.z; a.w += b.w;
    }
    const float dt = tspan[step + 1] - tspan[step];
    float4 qv = *reinterpret_cast<const float4*>(q + (long)n * FEAT + f0);
    float4 hv = *reinterpret_cast<const float4*>(hcur + (long)n * FEAT + f0);
    float s0 = qv.x + a.x * inv, s1 = qv.y + a.y * inv;
    float s2 = qv.z + a.z * inv, s3 = qv.w + a.w * inv;
    s0 = fminf(fmaxf(s0, -1000.f), 1000.f); s1 = fminf(fmaxf(s1, -1000.f), 1000.f);
    s2 = fminf(fmaxf(s2, -1000.f), 1000.f); s3 = fminf(fmaxf(s3, -1000.f), 1000.f);
    float4 o = {hv.x + dt * s0, hv.y + dt * s1, hv.z + dt * s2, hv.w + dt * s3};
    *reinterpret_cast<float4*>(hnext + (long)n * FEAT + f0) = o;
}

extern "C" void kernel_launch(void* const* d_in, const int* in_sizes, int n_in,
                              void* d_out, int out_size, void* d_ws, size_t ws_size,
                              hipStream_t stream) {
    const float* tspan = (const float*)d_in[0];
    const float* x     = (const float*)d_in[1];
    const float* adj   = (const float*)d_in[2];
    const float* We1   = (const float*)d_in[3];
    const float* be1   = (const float*)d_in[4];
    const float* We2   = (const float*)d_in[5];
    const float* be2   = (const float*)d_in[6];
    const float* Wf1   = (const float*)d_in[7];
    const float* bf1   = (const float*)d_in[8];
    const float* Wf2   = (const float*)d_in[9];
    const float* bf2   = (const float*)d_in[10];
    const float* Wl1   = (const float*)d_in[11];
    const float* bl1   = (const float*)d_in[12];
    const float* Wr1   = (const float*)d_in[13];
    const float* Wl2   = (const float*)d_in[14];
    const float* bl2   = (const float*)d_in[15];
    const float* Wr2   = (const float*)d_in[16];
    float* out = (float*)d_out;

    // workspace layout (bytes)
    char* ws = (char*)d_ws;
    int*   lists = (int*)  (ws + 0);           // 8000*64*4  = 2,048,000
    int*   cnt   = (int*)  (ws + 2048000);     // 32,000
    float* degf  = (float*)(ws + 2080000);     // 32,000
    float* Ws1   = (float*)(ws + 2112000);     // 65,536
    float* Wc2   = (float*)(ws + 2177536);     // 65,536
    float* pl    = (float*)(ws + 2243072);     // 2,048,000
    float* q     = (float*)(ws + 4291072);     // 2,048,000
    // total 6,339,072 bytes

    zero_cnt_kernel<<<32, 256, 0, stream>>>(cnt);
    build_adj_kernel<<<62500, 256, 0, stream>>>(adj, cnt, lists);
    prep_kernel<<<2128, 256, 0, stream>>>(cnt, lists, degf, Wl1, Wr1, Wl2, Wr2, Ws1, Wc2);
    init_enc_kernel<<<500, 256, 0, stream>>>(x, We1, be1, We2, be2, out);

    for (int s = 0; s < 3; ++s) {
        const float* hcur  = out + (long)s       * N_NODES * FEAT;
        float*       hnext = out + (long)(s + 1) * N_NODES * FEAT;
        sageproj_kernel<<<500, 256, 0, stream>>>(hcur, lists, cnt, degf,
                                                 Ws1, bl1, Wc2, bl2,
                                                 Wf1, bf1, Wf2, bf2, pl, q);
        epi_kernel<<<500, 256, 0, stream>>>(pl, q, lists, cnt, degf, hcur, tspan, s, hnext);
    }
}